// Round 16
// baseline (736.685 us; speedup 1.0000x reference)
//
#include <hip/hip_runtime.h>
#include <hip/hip_bf16.h>
#include <cstddef>

#define N_NODES 50000
#define N_EDGES 1600000
#define D 128
#define TWO_D 256
#define L 3
#define EPS 1e-7f
#define LN_EPS 1e-5f
#define MAXDEG 96   // deg ~ Poisson(32); P(deg>96) ~ 1e-20 per node. pos<96 clamp guards OOB.

typedef __attribute__((ext_vector_type(8))) short short8;
typedef __attribute__((ext_vector_type(4))) float f32x4;
typedef __attribute__((ext_vector_type(4))) unsigned u32x4;

__device__ __forceinline__ unsigned short f2bf(float f) {
    unsigned u = __float_as_uint(f);
    unsigned r = (u + 0x7fffu + ((u >> 16) & 1u)) >> 16;
    return (unsigned short)r;
}
__device__ __forceinline__ float bflo(unsigned u) { return __uint_as_float(u << 16); }
__device__ __forceinline__ float bfhi(unsigned u) { return __uint_as_float(u & 0xffff0000u); }
__device__ __forceinline__ unsigned bfpack(float lo, float hi) {
    return (unsigned)f2bf(lo) | ((unsigned)f2bf(hi) << 16);
}

// ---------------- build: pack weights + fused hist/scatter (padded CSR) + x->bf16 ----------------
// blocks [0,768): pack W1/W2 -> MFMA B-fragment order
// blocks [768,2816): fused histogram+scatter: atomicAdd return = slot within row;
//                    es2[dst*MAXDEG+pos] written immediately (no scan, no second pass)
// blocks [2816,...): x (f32) -> xb (bf16)

__global__ __launch_bounds__(256) void build_kernel(const int* __restrict__ ei, int* __restrict__ deg,
                                                    int2* __restrict__ es2,
                                                    const float* __restrict__ W1, const float* __restrict__ W2,
                                                    ushort* __restrict__ w1p, ushort* __restrict__ w2p,
                                                    const float* __restrict__ x, ushort2* __restrict__ xb) {
    int b = blockIdx.x;
    if (b < 768) {
        int tid = b * 256 + threadIdx.x;   // < 3*65536
        int layer = tid >> 16, t2 = tid & 65535;
        if (t2 < 32768) {
            int j = t2 & 7, l = (t2 >> 3) & 63, kk = (t2 >> 9) & 3, ct = t2 >> 11;
            int k = kk * 32 + (l >> 4) * 8 + j, n = ct * 16 + (l & 15);
            w1p[(size_t)layer * 32768 + t2] = f2bf(W1[(size_t)layer * 32768 + k * 256 + n]);
        } else {
            int t3 = t2 - 32768;
            int j = t3 & 7, l = (t3 >> 3) & 63, kk = (t3 >> 9) & 7, ct = t3 >> 12;
            int k = kk * 32 + (l >> 4) * 8 + j, n = ct * 16 + (l & 15);
            w2p[(size_t)layer * 32768 + t3] = f2bf(W2[(size_t)layer * 32768 + k * 128 + n]);
        }
    } else if (b < 2816) {
        int idx = (b - 768) * 256 + threadIdx.x;
        int stride = 2048 * 256;
        for (int e = idx; e < N_EDGES; e += stride) {
            int dn = ei[N_EDGES + e];
            int pos = atomicAdd(&deg[dn], 1);
            if (pos < MAXDEG)
                es2[(size_t)dn * MAXDEG + pos] = make_int2(ei[e], e);
        }
    } else {
        int i = (b - 2816) * 256 + threadIdx.x;   // one float2 per thread
        if (i < N_NODES * (D / 2)) {
            float2 v = *(const float2*)(x + (size_t)i * 2);
            ushort2 o;
            o.x = f2bf(v.x);
            o.y = f2bf(v.y);
            xb[i] = o;
        }
    }
}

// ---------------- Softmax aggregation: 8 edges x 8 feature-blocks per wave ----------------
// Padded CSR: row d occupies es2/eab slots [d*MAXDEG, d*MAXDEG+deg[d]).
// PREP=1 (layer 0): reads ea f32 via edge-id gather, writes eab bf16 as side effect.
// PREP=0: reads eab bf16 sequentially. Node gathers from bf16 table (xb / hnb).
// es2 row batch-loaded once, shfl-distributed (register-resident gather addresses).

template <int PREP>
__global__ __launch_bounds__(256) void aggregate_kernel(const uint4* __restrict__ nodeb,
                                                        const float* __restrict__ ea,
                                                        ushort* __restrict__ eab,
                                                        const int* __restrict__ deg_arr,
                                                        const int2* __restrict__ es2,
                                                        const float* __restrict__ beta, int layer,
                                                        ushort* __restrict__ preb) {
    int wid = threadIdx.x >> 6, lane = threadIdx.x & 63;
    int d = blockIdx.x * 4 + wid;
    if (d >= N_NODES) return;
    int e8 = lane >> 3;
    int f8 = lane & 7;
    float bet = beta[layer];
    int deg = min(deg_arr[d], MAXDEG);
    int j0 = d * MAXDEG, j1 = j0 + deg;

    // early residual load (consumed at the end; hidden under the edge loop)
    uint4 r0 = nodeb[(size_t)d * 16 + f8 * 2 + 0];
    uint4 r1 = nodeb[(size_t)d * 16 + f8 * 2 + 1];

    float se[16], sm[16];
#pragma unroll
    for (int i = 0; i < 16; ++i) { se[i] = 0.f; sm[i] = 0.f; }

    if (deg > 0) {
        int2 mp = (lane < deg) ? es2[j0 + lane] : make_int2(0, 0);
        bool small = (deg <= 64);
#pragma unroll 4
        for (int j = j0; j < j1; j += 8) {
            int e = j + e8;
            bool valid = e < j1;
            int ec = valid ? e : j1 - 1;
            int s, eid;
            if (small) {
                s   = __shfl(mp.x, ec - j0);
                eid = __shfl(mp.y, ec - j0);
            } else {
                int2 p = es2[ec];
                s = p.x; eid = p.y;
            }
            uint4 h0 = nodeb[(size_t)s * 16 + f8 * 2 + 0];
            uint4 h1 = nodeb[(size_t)s * 16 + f8 * 2 + 1];
            const unsigned* hu = (const unsigned*)&h0;
            const unsigned* hv = (const unsigned*)&h1;
            float vm = valid ? 1.f : 0.f;
            float af[16];
            if (PREP) {
                const float* ep = ea + (size_t)eid * D + f8 * 16;
                f32x4 fa0 = *(const f32x4*)(ep + 0);
                f32x4 fa1 = *(const f32x4*)(ep + 4);
                f32x4 fa2 = *(const f32x4*)(ep + 8);
                f32x4 fa3 = *(const f32x4*)(ep + 12);
#pragma unroll
                for (int q = 0; q < 4; ++q) {
                    af[q] = fa0[q];
                    af[4 + q] = fa1[q];
                    af[8 + q] = fa2[q];
                    af[12 + q] = fa3[q];
                }
                if (valid) {
                    u32x4 o0, o1;
                    o0[0] = bfpack(af[0], af[1]);  o0[1] = bfpack(af[2], af[3]);
                    o0[2] = bfpack(af[4], af[5]);  o0[3] = bfpack(af[6], af[7]);
                    o1[0] = bfpack(af[8], af[9]);  o1[1] = bfpack(af[10], af[11]);
                    o1[2] = bfpack(af[12], af[13]); o1[3] = bfpack(af[14], af[15]);
                    u32x4* dst = (u32x4*)(eab + (size_t)ec * D + f8 * 16);
                    dst[0] = o0;
                    dst[1] = o1;
                }
            } else {
                const u32x4* ap = (const u32x4*)(eab + (size_t)ec * D + f8 * 16);
                u32x4 a0 = ap[0];
                u32x4 a1 = ap[1];
#pragma unroll
                for (int q = 0; q < 4; ++q) {
                    af[q * 2 + 0] = bflo(a0[q]); af[q * 2 + 1] = bfhi(a0[q]);
                    af[8 + q * 2 + 0] = bflo(a1[q]); af[8 + q * 2 + 1] = bfhi(a1[q]);
                }
            }
#pragma unroll
            for (int q = 0; q < 4; ++q) {
                float m0 = fmaxf(bflo(hu[q]) + af[q * 2 + 0], 0.f) + EPS;
                float m1 = fmaxf(bfhi(hu[q]) + af[q * 2 + 1], 0.f) + EPS;
                float ee0 = __expf(bet * m0) * vm;
                float ee1 = __expf(bet * m1) * vm;
                se[q * 2 + 0] += ee0; sm[q * 2 + 0] = fmaf(ee0, m0, sm[q * 2 + 0]);
                se[q * 2 + 1] += ee1; sm[q * 2 + 1] = fmaf(ee1, m1, sm[q * 2 + 1]);
            }
#pragma unroll
            for (int q = 0; q < 4; ++q) {
                float m0 = fmaxf(bflo(hv[q]) + af[8 + q * 2 + 0], 0.f) + EPS;
                float m1 = fmaxf(bfhi(hv[q]) + af[8 + q * 2 + 1], 0.f) + EPS;
                float ee0 = __expf(bet * m0) * vm;
                float ee1 = __expf(bet * m1) * vm;
                se[8 + q * 2 + 0] += ee0; sm[8 + q * 2 + 0] = fmaf(ee0, m0, sm[8 + q * 2 + 0]);
                se[8 + q * 2 + 1] += ee1; sm[8 + q * 2 + 1] = fmaf(ee1, m1, sm[8 + q * 2 + 1]);
            }
        }
    }

    // reduce over e8 (lane bits 3..5)
#pragma unroll
    for (int off = 8; off < 64; off <<= 1) {
#pragma unroll
        for (int i = 0; i < 16; ++i) {
            se[i] += __shfl_xor(se[i], off);
            sm[i] += __shfl_xor(sm[i], off);
        }
    }

    if (e8 == 0) {
        const unsigned* ru = (const unsigned*)&r0;
        const unsigned* rv = (const unsigned*)&r1;
        float v[16];
#pragma unroll
        for (int q = 0; q < 4; ++q) {
            v[q * 2 + 0] = bflo(ru[q]) + (se[q * 2 + 0] > 0.f ? sm[q * 2 + 0] / se[q * 2 + 0] : 0.f);
            v[q * 2 + 1] = bfhi(ru[q]) + (se[q * 2 + 1] > 0.f ? sm[q * 2 + 1] / se[q * 2 + 1] : 0.f);
            v[8 + q * 2 + 0] = bflo(rv[q]) + (se[8 + q * 2 + 0] > 0.f ? sm[8 + q * 2 + 0] / se[8 + q * 2 + 0] : 0.f);
            v[8 + q * 2 + 1] = bfhi(rv[q]) + (se[8 + q * 2 + 1] > 0.f ? sm[8 + q * 2 + 1] / se[8 + q * 2 + 1] : 0.f);
        }
        uint4 o0, o1;
        o0.x = bfpack(v[0], v[1]);   o0.y = bfpack(v[2], v[3]);
        o0.z = bfpack(v[4], v[5]);   o0.w = bfpack(v[6], v[7]);
        o1.x = bfpack(v[8], v[9]);   o1.y = bfpack(v[10], v[11]);
        o1.z = bfpack(v[12], v[13]); o1.w = bfpack(v[14], v[15]);
        uint4* dst = (uint4*)(preb + (size_t)d * D + f8 * 16);
        dst[0] = o0;
        dst[1] = o1;
    }
}

// ---------------- Fused MFMA MLP: relu(preb@W1+b1)@W2+b2 (+res), epilogue LN ----------------
// Block = 32 nodes, 4 waves. Wave w: row-tile rt=w&1 (16 nodes), col-half ch=w>>1.

__global__ __launch_bounds__(256) void mlp_kernel(const ushort* __restrict__ preb,
                                                  const ushort* __restrict__ w1p, const float* __restrict__ b1,
                                                  const ushort* __restrict__ w2p, const float* __restrict__ b2,
                                                  const float* __restrict__ res,
                                                  float* __restrict__ h_out,
                                                  const float* __restrict__ ln_s, const float* __restrict__ ln_b,
                                                  ushort* __restrict__ hnb_out,
                                                  const float* __restrict__ Wout, const float* __restrict__ bout,
                                                  float* __restrict__ out, int mode) {
    __shared__ ushort hid[32][264];   // bf16, +8 pad
    __shared__ float hid2[32][132];   // f32, +4 pad
    int t = threadIdx.x;
    int lane = t & 63, w = t >> 6;
    int rt = w & 1, ch = w >> 1;
    int node0 = blockIdx.x * 32;
    int l15 = lane & 15, l4 = lane >> 4;

    // ---- GEMM1 ----
    f32x4 acc[8];
#pragma unroll
    for (int ct = 0; ct < 8; ++ct) {
        float bb = b1[ch * 128 + ct * 16 + l15];
        f32x4 v = {bb, bb, bb, bb};
        acc[ct] = v;
    }
    const ushort* aprow = preb + (size_t)(node0 + rt * 16 + l15) * D + l4 * 8;
    const short8* w1f = (const short8*)w1p;
#pragma unroll
    for (int kk = 0; kk < 4; ++kk) {
        short8 a = *(const short8*)(aprow + kk * 32);
#pragma unroll
        for (int ct = 0; ct < 8; ++ct) {
            int ctg = ch * 8 + ct;
            short8 b = w1f[(ctg * 4 + kk) * 64 + lane];
            acc[ct] = __builtin_amdgcn_mfma_f32_16x16x32_bf16(a, b, acc[ct], 0, 0, 0);
        }
    }
#pragma unroll
    for (int ct = 0; ct < 8; ++ct) {
        int feat = ch * 128 + ct * 16 + l15;
        int row = rt * 16 + l4 * 4;
#pragma unroll
        for (int r = 0; r < 4; ++r)
            hid[row + r][feat] = f2bf(fmaxf(acc[ct][r], 0.f));
    }
    __syncthreads();

    // ---- GEMM2 ----
    f32x4 acc2[4];
#pragma unroll
    for (int ct = 0; ct < 4; ++ct) {
        f32x4 z = {0.f, 0.f, 0.f, 0.f};
        acc2[ct] = z;
    }
    const ushort* ahrow = &hid[rt * 16 + l15][l4 * 8];
    const short8* w2f = (const short8*)w2p;
#pragma unroll
    for (int kk = 0; kk < 8; ++kk) {
        short8 a = *(const short8*)(ahrow + kk * 32);
#pragma unroll
        for (int ct = 0; ct < 4; ++ct) {
            int ctg = ch * 4 + ct;
            short8 b = w2f[(ctg * 8 + kk) * 64 + lane];
            acc2[ct] = __builtin_amdgcn_mfma_f32_16x16x32_bf16(a, b, acc2[ct], 0, 0, 0);
        }
    }
#pragma unroll
    for (int ct = 0; ct < 4; ++ct) {
        int feat = ch * 64 + ct * 16 + l15;
        int row = rt * 16 + l4 * 4;
#pragma unroll
        for (int r = 0; r < 4; ++r)
            hid2[row + r][feat] = acc2[ct][r];
    }
    __syncthreads();

    // ---- epilogue: +b2 (+res), LN, outputs ----
    int f4 = (t & 31) * 4;
    int ng = t >> 5;
    float4 b2v = *(const float4*)(b2 + f4);
#pragma unroll 1
    for (int n = 0; n < 4; ++n) {
        int nl = ng * 4 + n;
        int node = node0 + nl;
        bool valid = node < N_NODES;
        float4 v = *(float4*)&hid2[nl][f4];
        v.x += b2v.x; v.y += b2v.y; v.z += b2v.z; v.w += b2v.w;
        if (res != nullptr && valid) {
            float4 rv = *(const float4*)(res + (size_t)node * D + f4);
            v.x += rv.x; v.y += rv.y; v.z += rv.z; v.w += rv.w;
        }
        if (mode < 2 && valid) *(float4*)(h_out + (size_t)node * D + f4) = v;

        float s = v.x + v.y + v.z + v.w;
        for (int off = 16; off; off >>= 1) s += __shfl_xor(s, off);
        float mu = s * (1.0f / D);
        float dx = v.x - mu, dy = v.y - mu, dz = v.z - mu, dw = v.w - mu;
        float vs = dx * dx + dy * dy + dz * dz + dw * dw;
        for (int off = 16; off; off >>= 1) vs += __shfl_xor(vs, off);
        float r = rsqrtf(vs * (1.0f / D) + LN_EPS);
        float4 sc = *(const float4*)(ln_s + f4);
        float4 bi = *(const float4*)(ln_b + f4);
        float y0 = fmaxf(dx * r * sc.x + bi.x, 0.f);
        float y1 = fmaxf(dy * r * sc.y + bi.y, 0.f);
        float y2 = fmaxf(dz * r * sc.z + bi.z, 0.f);
        float y3 = fmaxf(dw * r * sc.w + bi.w, 0.f);
        if (mode < 2) {
            if (valid) {
                ushort4 hb;
                hb.x = f2bf(y0); hb.y = f2bf(y1); hb.z = f2bf(y2); hb.w = f2bf(y3);
                *(ushort4*)(hnb_out + (size_t)node * D + f4) = hb;
            }
        } else {
            float4 wv = *(const float4*)(Wout + f4);
            float dot = y0 * wv.x + y1 * wv.y + y2 * wv.z + y3 * wv.w;
            for (int off = 16; off; off >>= 1) dot += __shfl_xor(dot, off);
            if ((t & 31) == 0 && valid) out[node] = dot + bout[0];
        }
    }
}

// ---------------- launch ----------------

extern "C" void kernel_launch(void* const* d_in, const int* in_sizes, int n_in,
                              void* d_out, int out_size, void* d_ws, size_t ws_size,
                              hipStream_t stream) {
    const float* x        = (const float*)d_in[0];
    const int*   ei       = (const int*)d_in[1];
    const float* ea       = (const float*)d_in[2];
    const float* ln_scale = (const float*)d_in[3];
    const float* ln_bias  = (const float*)d_in[4];
    const float* W1       = (const float*)d_in[5];
    const float* b1       = (const float*)d_in[6];
    const float* W2       = (const float*)d_in[7];
    const float* b2       = (const float*)d_in[8];
    const float* beta     = (const float*)d_in[9];
    const float* lnf_s    = (const float*)d_in[10];
    const float* lnf_b    = (const float*)d_in[11];
    const float* Wout     = (const float*)d_in[12];
    const float* bout     = (const float*)d_in[13];
    float* out = (float*)d_out;

    char* w = (char*)d_ws;
    ushort* eab  = (ushort*)w; w += (size_t)N_NODES * MAXDEG * D * 2;  // 1228.8 MB (padded)
    int2* es2    = (int2*)w;   w += (size_t)N_NODES * MAXDEG * 8;      // 38.4 MB (padded)
    float*  h    = (float*)w;  w += (size_t)N_NODES * D * 4;           // 25.6 MB
    ushort* preb = (ushort*)w; w += (size_t)N_NODES * D * 2;           // 12.8 MB
    ushort* hnb  = (ushort*)w; w += (size_t)N_NODES * D * 2;           // 12.8 MB
    ushort* xb   = (ushort*)w; w += (size_t)N_NODES * D * 2;           // 12.8 MB
    ushort* w1p  = (ushort*)w; w += (size_t)3 * 32768 * 2;
    ushort* w2p  = (ushort*)w; w += (size_t)3 * 32768 * 2;
    int* deg     = (int*)w;    w += (size_t)N_NODES * 4;

    const int XB = (N_NODES * (D / 2) + 255) / 256;  // 12500

    hipMemsetAsync(deg, 0, (size_t)N_NODES * 4, stream);
    build_kernel<<<2816 + XB, 256, 0, stream>>>(ei, deg, es2, W1, W2, w1p, w2p, x, (ushort2*)xb);

    const int grid_rows = (N_NODES + 3) / 4;     // 12500
    const int grid_gemm = (N_NODES + 31) / 32;   // 1563

    for (int layer = 0; layer < L; ++layer) {
        const uint4* nodeb = (const uint4*)((layer == 0) ? xb : hnb);
        if (layer == 0)
            aggregate_kernel<1><<<grid_rows, 256, 0, stream>>>(nodeb, ea, eab, deg, es2, beta, layer, preb);
        else
            aggregate_kernel<0><<<grid_rows, 256, 0, stream>>>(nodeb, ea, eab, deg, es2, beta, layer, preb);

        if (layer < L - 1) {
            mlp_kernel<<<grid_gemm, 256, 0, stream>>>(preb,
                                                      w1p + (size_t)layer * 32768, b1 + (size_t)layer * TWO_D,
                                                      w2p + (size_t)layer * 32768, b2 + (size_t)layer * D,
                                                      layer == 0 ? nullptr : h, h,
                                                      ln_scale + (size_t)(layer + 1) * D,
                                                      ln_bias + (size_t)(layer + 1) * D,
                                                      hnb, nullptr, nullptr, nullptr, layer == 0 ? 0 : 1);
        } else {
            mlp_kernel<<<grid_gemm, 256, 0, stream>>>(preb,
                                                      w1p + (size_t)layer * 32768, b1 + (size_t)layer * TWO_D,
                                                      w2p + (size_t)layer * 32768, b2 + (size_t)layer * D,
                                                      h, nullptr,
                                                      lnf_s, lnf_b, nullptr,
                                                      Wout, bout, out, 2);
        }
    }
}

// Round 17
// 726.888 us; speedup vs baseline: 1.0135x; 1.0135x over previous
//
#include <hip/hip_runtime.h>
#include <hip/hip_bf16.h>
#include <cstddef>

#define N_NODES 50000
#define N_EDGES 1600000
#define D 128
#define TWO_D 256
#define L 3
#define EPS 1e-7f
#define LN_EPS 1e-5f

typedef __attribute__((ext_vector_type(8))) short short8;
typedef __attribute__((ext_vector_type(4))) float f32x4;
typedef __attribute__((ext_vector_type(4))) unsigned u32x4;

__device__ __forceinline__ unsigned short f2bf(float f) {
    unsigned u = __float_as_uint(f);
    unsigned r = (u + 0x7fffu + ((u >> 16) & 1u)) >> 16;
    return (unsigned short)r;
}
__device__ __forceinline__ float bflo(unsigned u) { return __uint_as_float(u << 16); }
__device__ __forceinline__ float bfhi(unsigned u) { return __uint_as_float(u & 0xffff0000u); }
__device__ __forceinline__ unsigned bfpack(float lo, float hi) {
    return (unsigned)f2bf(lo) | ((unsigned)f2bf(hi) << 16);
}

// ---------------- build: pack weights + degree histogram (records slot pos) + x->bf16 ----------------
// blocks [0,768): pack W1/W2 -> MFMA B-fragment order
// blocks [768,2816): degree histogram; atomicAdd return value = edge's slot within its row
// blocks [2816,...): x (f32) -> xb (bf16)

__global__ __launch_bounds__(256) void build_kernel(const int* __restrict__ ei, int* __restrict__ deg,
                                                    int* __restrict__ slotpos,
                                                    const float* __restrict__ W1, const float* __restrict__ W2,
                                                    ushort* __restrict__ w1p, ushort* __restrict__ w2p,
                                                    const float* __restrict__ x, ushort2* __restrict__ xb) {
    int b = blockIdx.x;
    if (b < 768) {
        int tid = b * 256 + threadIdx.x;   // < 3*65536
        int layer = tid >> 16, t2 = tid & 65535;
        if (t2 < 32768) {
            int j = t2 & 7, l = (t2 >> 3) & 63, kk = (t2 >> 9) & 3, ct = t2 >> 11;
            int k = kk * 32 + (l >> 4) * 8 + j, n = ct * 16 + (l & 15);
            w1p[(size_t)layer * 32768 + t2] = f2bf(W1[(size_t)layer * 32768 + k * 256 + n]);
        } else {
            int t3 = t2 - 32768;
            int j = t3 & 7, l = (t3 >> 3) & 63, kk = (t3 >> 9) & 7, ct = t3 >> 12;
            int k = kk * 32 + (l >> 4) * 8 + j, n = ct * 16 + (l & 15);
            w2p[(size_t)layer * 32768 + t3] = f2bf(W2[(size_t)layer * 32768 + k * 128 + n]);
        }
    } else if (b < 2816) {
        int idx = (b - 768) * 256 + threadIdx.x;
        int stride = 2048 * 256;
        for (int e = idx; e < N_EDGES; e += stride)
            slotpos[e] = atomicAdd(&deg[ei[N_EDGES + e]], 1);
    } else {
        int i = (b - 2816) * 256 + threadIdx.x;   // one float2 per thread
        if (i < N_NODES * (D / 2)) {
            float2 v = *(const float2*)(x + (size_t)i * 2);
            ushort2 o;
            o.x = f2bf(v.x);
            o.y = f2bf(v.y);
            xb[i] = o;
        }
    }
}

__global__ __launch_bounds__(256) void scanA_kernel(const int* __restrict__ deg, int* __restrict__ part,
                                                    int* __restrict__ bsum) {
    __shared__ int wsum[4];
    int b = blockIdx.x, t = threadIdx.x;
    int lane = t & 63, wid = t >> 6;
    int base = b * 1024 + t * 4;
    int v0 = 0, v1 = 0, v2 = 0, v3 = 0;
    if (base + 0 < N_NODES) v0 = deg[base + 0];
    if (base + 1 < N_NODES) v1 = deg[base + 1];
    if (base + 2 < N_NODES) v2 = deg[base + 2];
    if (base + 3 < N_NODES) v3 = deg[base + 3];
    int s0 = v0, s1 = s0 + v1, s2 = s1 + v2, s3 = s2 + v3;
    int inc = s3;
    for (int off = 1; off < 64; off <<= 1) {
        int u = __shfl_up(inc, off);
        if (lane >= off) inc += u;
    }
    if (lane == 63) wsum[wid] = inc;
    __syncthreads();
    int woff = 0;
    for (int w = 0; w < wid; ++w) woff += wsum[w];
    int excl = woff + inc - s3;
    if (base + 0 < N_NODES) part[base + 0] = excl + s0;
    if (base + 1 < N_NODES) part[base + 1] = excl + s1;
    if (base + 2 < N_NODES) part[base + 2] = excl + s2;
    if (base + 3 < N_NODES) part[base + 3] = excl + s3;
    if (t == 255) bsum[b] = woff + inc;
}

// scan of 49 block sums re-derived per block (no separate 1-block kernel)
__global__ __launch_bounds__(256) void scan2_kernel(const int* __restrict__ part, const int* __restrict__ bsum,
                                                    int nb, int* __restrict__ rowptr) {
    __shared__ int excl[64];
    int t = threadIdx.x;
    if (t < 64) {
        int v = (t < nb) ? bsum[t] : 0;
        int inc = v;
        for (int off = 1; off < 64; off <<= 1) {
            int u = __shfl_up(inc, off);
            if (t >= off) inc += u;
        }
        excl[t] = inc - v;
    }
    __syncthreads();
    int i = blockIdx.x * blockDim.x + t;
    if (i >= N_NODES) return;
    rowptr[i + 1] = part[i] + excl[i >> 10];
    if (i == 0) rowptr[0] = 0;
}

// es2[slot] = (src node, edge id); slot = rowptr[dst] + slotpos[e] -> NO atomics
__global__ __launch_bounds__(256) void scatter_kernel(const int* __restrict__ ei, const int* __restrict__ rowptr,
                                                      const int* __restrict__ slotpos, int2* __restrict__ es2) {
    int idx = blockIdx.x * blockDim.x + threadIdx.x;
    int stride = gridDim.x * blockDim.x;
    for (int e = idx; e < N_EDGES; e += stride) {
        int dn = ei[N_EDGES + e];
        es2[rowptr[dn] + slotpos[e]] = make_int2(ei[e], e);
    }
}

// ---------------- Softmax aggregation: 8 edges x 8 feature-blocks per wave ----------------
// PREP=1 (layer 0): reads ea f32 via edge-id gather, writes eab bf16 (CSR order) as side effect.
// PREP=0: reads eab bf16 sequentially. Node gathers always from bf16 table (xb / hnb).
// es2 row batch-loaded once and shfl-distributed (keeps gather addresses register-resident).

template <int PREP>
__global__ __launch_bounds__(256) void aggregate_kernel(const uint4* __restrict__ nodeb,
                                                        const float* __restrict__ ea,
                                                        ushort* __restrict__ eab,
                                                        const int* __restrict__ rowptr,
                                                        const int2* __restrict__ es2,
                                                        const float* __restrict__ beta, int layer,
                                                        ushort* __restrict__ preb) {
    int wid = threadIdx.x >> 6, lane = threadIdx.x & 63;
    int d = blockIdx.x * 4 + wid;
    if (d >= N_NODES) return;
    int e8 = lane >> 3;
    int f8 = lane & 7;
    float bet = beta[layer];
    int j0 = rowptr[d], j1 = rowptr[d + 1];
    int deg = j1 - j0;

    // early residual load (consumed at the end; hidden under the edge loop)
    uint4 r0 = nodeb[(size_t)d * 16 + f8 * 2 + 0];
    uint4 r1 = nodeb[(size_t)d * 16 + f8 * 2 + 1];

    float se[16], sm[16];
#pragma unroll
    for (int i = 0; i < 16; ++i) { se[i] = 0.f; sm[i] = 0.f; }

    if (deg > 0) {
        int2 mp = (j0 + lane < j1) ? es2[j0 + lane] : make_int2(0, 0);
        bool small = (deg <= 64);
#pragma unroll 4
        for (int j = j0; j < j1; j += 8) {
            int e = j + e8;
            bool valid = e < j1;
            int ec = valid ? e : j1 - 1;
            int s, eid;
            if (small) {
                s   = __shfl(mp.x, ec - j0);
                eid = __shfl(mp.y, ec - j0);
            } else {
                int2 p = es2[ec];
                s = p.x; eid = p.y;
            }
            uint4 h0 = nodeb[(size_t)s * 16 + f8 * 2 + 0];
            uint4 h1 = nodeb[(size_t)s * 16 + f8 * 2 + 1];
            const unsigned* hu = (const unsigned*)&h0;
            const unsigned* hv = (const unsigned*)&h1;
            float vm = valid ? 1.f : 0.f;
            float af[16];
            if (PREP) {
                const float* ep = ea + (size_t)eid * D + f8 * 16;
                f32x4 fa0 = *(const f32x4*)(ep + 0);
                f32x4 fa1 = *(const f32x4*)(ep + 4);
                f32x4 fa2 = *(const f32x4*)(ep + 8);
                f32x4 fa3 = *(const f32x4*)(ep + 12);
#pragma unroll
                for (int q = 0; q < 4; ++q) {
                    af[q] = fa0[q];
                    af[4 + q] = fa1[q];
                    af[8 + q] = fa2[q];
                    af[12 + q] = fa3[q];
                }
                if (valid) {
                    u32x4 o0, o1;
                    o0[0] = bfpack(af[0], af[1]);  o0[1] = bfpack(af[2], af[3]);
                    o0[2] = bfpack(af[4], af[5]);  o0[3] = bfpack(af[6], af[7]);
                    o1[0] = bfpack(af[8], af[9]);  o1[1] = bfpack(af[10], af[11]);
                    o1[2] = bfpack(af[12], af[13]); o1[3] = bfpack(af[14], af[15]);
                    u32x4* dst = (u32x4*)(eab + (size_t)ec * D + f8 * 16);
                    dst[0] = o0;
                    dst[1] = o1;
                }
            } else {
                const u32x4* ap = (const u32x4*)(eab + (size_t)ec * D + f8 * 16);
                u32x4 a0 = ap[0];
                u32x4 a1 = ap[1];
#pragma unroll
                for (int q = 0; q < 4; ++q) {
                    af[q * 2 + 0] = bflo(a0[q]); af[q * 2 + 1] = bfhi(a0[q]);
                    af[8 + q * 2 + 0] = bflo(a1[q]); af[8 + q * 2 + 1] = bfhi(a1[q]);
                }
            }
#pragma unroll
            for (int q = 0; q < 4; ++q) {
                float m0 = fmaxf(bflo(hu[q]) + af[q * 2 + 0], 0.f) + EPS;
                float m1 = fmaxf(bfhi(hu[q]) + af[q * 2 + 1], 0.f) + EPS;
                float ee0 = __expf(bet * m0) * vm;
                float ee1 = __expf(bet * m1) * vm;
                se[q * 2 + 0] += ee0; sm[q * 2 + 0] = fmaf(ee0, m0, sm[q * 2 + 0]);
                se[q * 2 + 1] += ee1; sm[q * 2 + 1] = fmaf(ee1, m1, sm[q * 2 + 1]);
            }
#pragma unroll
            for (int q = 0; q < 4; ++q) {
                float m0 = fmaxf(bflo(hv[q]) + af[8 + q * 2 + 0], 0.f) + EPS;
                float m1 = fmaxf(bfhi(hv[q]) + af[8 + q * 2 + 1], 0.f) + EPS;
                float ee0 = __expf(bet * m0) * vm;
                float ee1 = __expf(bet * m1) * vm;
                se[8 + q * 2 + 0] += ee0; sm[8 + q * 2 + 0] = fmaf(ee0, m0, sm[8 + q * 2 + 0]);
                se[8 + q * 2 + 1] += ee1; sm[8 + q * 2 + 1] = fmaf(ee1, m1, sm[8 + q * 2 + 1]);
            }
        }
    }

    // reduce over e8 (lane bits 3..5)
#pragma unroll
    for (int off = 8; off < 64; off <<= 1) {
#pragma unroll
        for (int i = 0; i < 16; ++i) {
            se[i] += __shfl_xor(se[i], off);
            sm[i] += __shfl_xor(sm[i], off);
        }
    }

    if (e8 == 0) {
        const unsigned* ru = (const unsigned*)&r0;
        const unsigned* rv = (const unsigned*)&r1;
        float v[16];
#pragma unroll
        for (int q = 0; q < 4; ++q) {
            v[q * 2 + 0] = bflo(ru[q]) + (se[q * 2 + 0] > 0.f ? sm[q * 2 + 0] / se[q * 2 + 0] : 0.f);
            v[q * 2 + 1] = bfhi(ru[q]) + (se[q * 2 + 1] > 0.f ? sm[q * 2 + 1] / se[q * 2 + 1] : 0.f);
            v[8 + q * 2 + 0] = bflo(rv[q]) + (se[8 + q * 2 + 0] > 0.f ? sm[8 + q * 2 + 0] / se[8 + q * 2 + 0] : 0.f);
            v[8 + q * 2 + 1] = bfhi(rv[q]) + (se[8 + q * 2 + 1] > 0.f ? sm[8 + q * 2 + 1] / se[8 + q * 2 + 1] : 0.f);
        }
        uint4 o0, o1;
        o0.x = bfpack(v[0], v[1]);   o0.y = bfpack(v[2], v[3]);
        o0.z = bfpack(v[4], v[5]);   o0.w = bfpack(v[6], v[7]);
        o1.x = bfpack(v[8], v[9]);   o1.y = bfpack(v[10], v[11]);
        o1.z = bfpack(v[12], v[13]); o1.w = bfpack(v[14], v[15]);
        uint4* dst = (uint4*)(preb + (size_t)d * D + f8 * 16);
        dst[0] = o0;
        dst[1] = o1;
    }
}

// ---------------- Fused MFMA MLP: relu(preb@W1+b1)@W2+b2 (+res), epilogue LN ----------------
// Block = 32 nodes, 4 waves. Wave w: row-tile rt=w&1 (16 nodes), col-half ch=w>>1.

__global__ __launch_bounds__(256) void mlp_kernel(const ushort* __restrict__ preb,
                                                  const ushort* __restrict__ w1p, const float* __restrict__ b1,
                                                  const ushort* __restrict__ w2p, const float* __restrict__ b2,
                                                  const float* __restrict__ res,
                                                  float* __restrict__ h_out,
                                                  const float* __restrict__ ln_s, const float* __restrict__ ln_b,
                                                  ushort* __restrict__ hnb_out,
                                                  const float* __restrict__ Wout, const float* __restrict__ bout,
                                                  float* __restrict__ out, int mode) {
    __shared__ ushort hid[32][264];   // bf16, +8 pad
    __shared__ float hid2[32][132];   // f32, +4 pad
    int t = threadIdx.x;
    int lane = t & 63, w = t >> 6;
    int rt = w & 1, ch = w >> 1;
    int node0 = blockIdx.x * 32;
    int l15 = lane & 15, l4 = lane >> 4;

    // ---- GEMM1 ----
    f32x4 acc[8];
#pragma unroll
    for (int ct = 0; ct < 8; ++ct) {
        float bb = b1[ch * 128 + ct * 16 + l15];
        f32x4 v = {bb, bb, bb, bb};
        acc[ct] = v;
    }
    const ushort* aprow = preb + (size_t)(node0 + rt * 16 + l15) * D + l4 * 8;
    const short8* w1f = (const short8*)w1p;
#pragma unroll
    for (int kk = 0; kk < 4; ++kk) {
        short8 a = *(const short8*)(aprow + kk * 32);
#pragma unroll
        for (int ct = 0; ct < 8; ++ct) {
            int ctg = ch * 8 + ct;
            short8 b = w1f[(ctg * 4 + kk) * 64 + lane];
            acc[ct] = __builtin_amdgcn_mfma_f32_16x16x32_bf16(a, b, acc[ct], 0, 0, 0);
        }
    }
#pragma unroll
    for (int ct = 0; ct < 8; ++ct) {
        int feat = ch * 128 + ct * 16 + l15;
        int row = rt * 16 + l4 * 4;
#pragma unroll
        for (int r = 0; r < 4; ++r)
            hid[row + r][feat] = f2bf(fmaxf(acc[ct][r], 0.f));
    }
    __syncthreads();

    // ---- GEMM2 ----
    f32x4 acc2[4];
#pragma unroll
    for (int ct = 0; ct < 4; ++ct) {
        f32x4 z = {0.f, 0.f, 0.f, 0.f};
        acc2[ct] = z;
    }
    const ushort* ahrow = &hid[rt * 16 + l15][l4 * 8];
    const short8* w2f = (const short8*)w2p;
#pragma unroll
    for (int kk = 0; kk < 8; ++kk) {
        short8 a = *(const short8*)(ahrow + kk * 32);
#pragma unroll
        for (int ct = 0; ct < 4; ++ct) {
            int ctg = ch * 4 + ct;
            short8 b = w2f[(ctg * 8 + kk) * 64 + lane];
            acc2[ct] = __builtin_amdgcn_mfma_f32_16x16x32_bf16(a, b, acc2[ct], 0, 0, 0);
        }
    }
#pragma unroll
    for (int ct = 0; ct < 4; ++ct) {
        int feat = ch * 64 + ct * 16 + l15;
        int row = rt * 16 + l4 * 4;
#pragma unroll
        for (int r = 0; r < 4; ++r)
            hid2[row + r][feat] = acc2[ct][r];
    }
    __syncthreads();

    // ---- epilogue: +b2 (+res), LN, outputs ----
    int f4 = (t & 31) * 4;
    int ng = t >> 5;
    float4 b2v = *(const float4*)(b2 + f4);
#pragma unroll 1
    for (int n = 0; n < 4; ++n) {
        int nl = ng * 4 + n;
        int node = node0 + nl;
        bool valid = node < N_NODES;
        float4 v = *(float4*)&hid2[nl][f4];
        v.x += b2v.x; v.y += b2v.y; v.z += b2v.z; v.w += b2v.w;
        if (res != nullptr && valid) {
            float4 rv = *(const float4*)(res + (size_t)node * D + f4);
            v.x += rv.x; v.y += rv.y; v.z += rv.z; v.w += rv.w;
        }
        if (mode < 2 && valid) *(float4*)(h_out + (size_t)node * D + f4) = v;

        float s = v.x + v.y + v.z + v.w;
        for (int off = 16; off; off >>= 1) s += __shfl_xor(s, off);
        float mu = s * (1.0f / D);
        float dx = v.x - mu, dy = v.y - mu, dz = v.z - mu, dw = v.w - mu;
        float vs = dx * dx + dy * dy + dz * dz + dw * dw;
        for (int off = 16; off; off >>= 1) vs += __shfl_xor(vs, off);
        float r = rsqrtf(vs * (1.0f / D) + LN_EPS);
        float4 sc = *(const float4*)(ln_s + f4);
        float4 bi = *(const float4*)(ln_b + f4);
        float y0 = fmaxf(dx * r * sc.x + bi.x, 0.f);
        float y1 = fmaxf(dy * r * sc.y + bi.y, 0.f);
        float y2 = fmaxf(dz * r * sc.z + bi.z, 0.f);
        float y3 = fmaxf(dw * r * sc.w + bi.w, 0.f);
        if (mode < 2) {
            if (valid) {
                ushort4 hb;
                hb.x = f2bf(y0); hb.y = f2bf(y1); hb.z = f2bf(y2); hb.w = f2bf(y3);
                *(ushort4*)(hnb_out + (size_t)node * D + f4) = hb;
            }
        } else {
            float4 wv = *(const float4*)(Wout + f4);
            float dot = y0 * wv.x + y1 * wv.y + y2 * wv.z + y3 * wv.w;
            for (int off = 16; off; off >>= 1) dot += __shfl_xor(dot, off);
            if ((t & 31) == 0 && valid) out[node] = dot + bout[0];
        }
    }
}

// ---------------- launch ----------------

extern "C" void kernel_launch(void* const* d_in, const int* in_sizes, int n_in,
                              void* d_out, int out_size, void* d_ws, size_t ws_size,
                              hipStream_t stream) {
    const float* x        = (const float*)d_in[0];
    const int*   ei       = (const int*)d_in[1];
    const float* ea       = (const float*)d_in[2];
    const float* ln_scale = (const float*)d_in[3];
    const float* ln_bias  = (const float*)d_in[4];
    const float* W1       = (const float*)d_in[5];
    const float* b1       = (const float*)d_in[6];
    const float* W2       = (const float*)d_in[7];
    const float* b2       = (const float*)d_in[8];
    const float* beta     = (const float*)d_in[9];
    const float* lnf_s    = (const float*)d_in[10];
    const float* lnf_b    = (const float*)d_in[11];
    const float* Wout     = (const float*)d_in[12];
    const float* bout     = (const float*)d_in[13];
    float* out = (float*)d_out;

    char* w = (char*)d_ws;
    float*  h    = (float*)w;  w += (size_t)N_NODES * D * 4;    // 25.6 MB
    ushort* preb = (ushort*)w; w += (size_t)N_NODES * D * 2;    // 12.8 MB
    ushort* hnb  = (ushort*)w; w += (size_t)N_NODES * D * 2;    // 12.8 MB
    ushort* xb   = (ushort*)w; w += (size_t)N_NODES * D * 2;    // 12.8 MB
    ushort* eab  = (ushort*)w; w += (size_t)N_EDGES * D * 2;    // 409.6 MB
    int2* es2   = (int2*)w;  w += (size_t)N_EDGES * 8;          // 12.8 MB
    int* slotpos = (int*)w;  w += (size_t)N_EDGES * 4;          // 6.4 MB
    ushort* w1p = (ushort*)w; w += (size_t)3 * 32768 * 2;
    ushort* w2p = (ushort*)w; w += (size_t)3 * 32768 * 2;
    int* deg    = (int*)w;   w += (size_t)N_NODES * 4;
    int* part   = (int*)w;   w += (size_t)50176 * 4;
    int* rowptr = (int*)w;   w += (size_t)(N_NODES + 1) * 4;
    int* bsum   = (int*)w;   w += (size_t)64 * 4;

    const int NB = (N_NODES + 1023) / 1024;   // 49
    const int XB = (N_NODES * (D / 2) + 255) / 256;  // 12500

    hipMemsetAsync(deg, 0, (size_t)N_NODES * 4, stream);
    build_kernel<<<2816 + XB, 256, 0, stream>>>(ei, deg, slotpos, W1, W2, w1p, w2p, x, (ushort2*)xb);
    scanA_kernel<<<NB, 256, 0, stream>>>(deg, part, bsum);
    scan2_kernel<<<(N_NODES + 255) / 256, 256, 0, stream>>>(part, bsum, NB, rowptr);
    scatter_kernel<<<2048, 256, 0, stream>>>(ei, rowptr, slotpos, es2);

    const int grid_rows = (N_NODES + 3) / 4;     // 12500
    const int grid_gemm = (N_NODES + 31) / 32;   // 1563

    for (int layer = 0; layer < L; ++layer) {
        const uint4* nodeb = (const uint4*)((layer == 0) ? xb : hnb);
        if (layer == 0)
            aggregate_kernel<1><<<grid_rows, 256, 0, stream>>>(nodeb, ea, eab, rowptr, es2, beta, layer, preb);
        else
            aggregate_kernel<0><<<grid_rows, 256, 0, stream>>>(nodeb, ea, eab, rowptr, es2, beta, layer, preb);

        if (layer < L - 1) {
            mlp_kernel<<<grid_gemm, 256, 0, stream>>>(preb,
                                                      w1p + (size_t)layer * 32768, b1 + (size_t)layer * TWO_D,
                                                      w2p + (size_t)layer * 32768, b2 + (size_t)layer * D,
                                                      layer == 0 ? nullptr : h, h,
                                                      ln_scale + (size_t)(layer + 1) * D,
                                                      ln_bias + (size_t)(layer + 1) * D,
                                                      hnb, nullptr, nullptr, nullptr, layer == 0 ? 0 : 1);
        } else {
            mlp_kernel<<<grid_gemm, 256, 0, stream>>>(preb,
                                                      w1p + (size_t)layer * 32768, b1 + (size_t)layer * TWO_D,
                                                      w2p + (size_t)layer * 32768, b2 + (size_t)layer * D,
                                                      h, nullptr,
                                                      lnf_s, lnf_b, nullptr,
                                                      Wout, bout, out, 2);
        }
    }
}